// Round 1
// baseline (632.259 us; speedup 1.0000x reference)
//
#include <hip/hip_runtime.h>
#include <math.h>

// Problem constants
#define Bsz 2
#define Tsz 1024
#define Dsz 2048
#define Hn 4
#define Kn 8
#define DKn 64
#define En 16384
#define NKn 128
#define NTOK (Bsz * Tsz)      // 2048 tokens
#define QCOLS (2 * Hn * DKn)  // 512
#define KSPLIT 4
#define KCHUNK (Dsz / KSPLIT) // 512

// ---------------------------------------------------------------------------
// Stage 1: q partials = x @ Wq, split-K by 4.
// Grid (32, 8, 4) = 1024 blocks -> 4 blocks/CU, 16 waves/CU.
// fp64 accumulation within each 512-deep chunk; fp32 partial out.
// 64x64 tile, BK=16, 256 threads, 4x4 microtile.
// ---------------------------------------------------------------------------
#define GM 64
#define GN 64
#define GK 16

__global__ __launch_bounds__(256) void gemm_q_kernel(
    const float* __restrict__ A,   // x: [NTOK, Dsz]
    const float* __restrict__ B,   // Wq: [Dsz, QCOLS]
    float* __restrict__ P)         // partials: [KSPLIT][NTOK][QCOLS]
{
    const int K = Dsz, N = QCOLS;
    __shared__ float As[GK][GM + 4];
    __shared__ float Bs[GK][GN + 4];

    const int tid = threadIdx.x;
    const int row0 = blockIdx.x * GM;
    const int col0 = blockIdx.y * GN;
    const int k0 = blockIdx.z * KCHUNK;
    const int tx = tid & 15;        // 0..15 (N dir)
    const int ty = tid >> 4;        // 0..15 (M dir)

    const int am = tid >> 2;
    const int ak = (tid & 3) << 2;
    const int bk = tid >> 4;
    const int bn = (tid & 15) << 2;

    double acc[4][4] = {};

    for (int kt = k0; kt < k0 + KCHUNK; kt += GK) {
        float4 av = *(const float4*)(A + (size_t)(row0 + am) * K + kt + ak);
        float4 bv = *(const float4*)(B + (size_t)(kt + bk) * N + col0 + bn);
        As[ak + 0][am] = av.x;
        As[ak + 1][am] = av.y;
        As[ak + 2][am] = av.z;
        As[ak + 3][am] = av.w;
        *(float4*)&Bs[bk][bn] = bv;
        __syncthreads();
#pragma unroll
        for (int k = 0; k < GK; k++) {
            float4 a = *(const float4*)&As[k][ty << 2];
            float4 b = *(const float4*)&Bs[k][tx << 2];
            double ax = a.x, ay = a.y, az = a.z, aw = a.w;
            double bx = b.x, by = b.y, bz = b.z, bw = b.w;
            acc[0][0] = fma(ax, bx, acc[0][0]);
            acc[0][1] = fma(ax, by, acc[0][1]);
            acc[0][2] = fma(ax, bz, acc[0][2]);
            acc[0][3] = fma(ax, bw, acc[0][3]);
            acc[1][0] = fma(ay, bx, acc[1][0]);
            acc[1][1] = fma(ay, by, acc[1][1]);
            acc[1][2] = fma(ay, bz, acc[1][2]);
            acc[1][3] = fma(ay, bw, acc[1][3]);
            acc[2][0] = fma(az, bx, acc[2][0]);
            acc[2][1] = fma(az, by, acc[2][1]);
            acc[2][2] = fma(az, bz, acc[2][2]);
            acc[2][3] = fma(az, bw, acc[2][3]);
            acc[3][0] = fma(aw, bx, acc[3][0]);
            acc[3][1] = fma(aw, by, acc[3][1]);
            acc[3][2] = fma(aw, bz, acc[3][2]);
            acc[3][3] = fma(aw, bw, acc[3][3]);
        }
        __syncthreads();
    }

    float* Pz = P + (size_t)blockIdx.z * NTOK * QCOLS;
#pragma unroll
    for (int i = 0; i < 4; i++) {
        float4 cv = make_float4((float)acc[i][0], (float)acc[i][1],
                                (float)acc[i][2], (float)acc[i][3]);
        *(float4*)(Pz + (size_t)(row0 + (ty << 2) + i) * N + col0 + (tx << 2)) = cv;
    }
}

// ---------------------------------------------------------------------------
// Stage 2: sum K-partials, sims + two-level top-k in fp64. One wave per (b,t,h).
// ---------------------------------------------------------------------------
__device__ inline void argmax64d(double& v, int& i) {
#pragma unroll
    for (int off = 1; off < 64; off <<= 1) {
        double ov = __shfl_xor(v, off);
        int oi = __shfl_xor(i, off);
        if (ov > v || (ov == v && oi < i)) { v = ov; i = oi; }
    }
}

__global__ __launch_bounds__(64) void select_kernel(
    const float* __restrict__ P,      // [KSPLIT][NTOK][QCOLS]
    const float* __restrict__ keys,   // [Hn, NKn, 2, DKn]
    int* __restrict__ fidx,           // [NTOK*Hn, Kn]
    float* __restrict__ fscore)       // [NTOK*Hn, Kn]
{
    const int bth = blockIdx.x;       // 8192
    const int token = bth >> 2;
    const int h = bth & 3;
    const int lane = threadIdx.x;

    __shared__ __align__(16) float q1s[64];
    __shared__ __align__(16) float q2s[64];
    {
        const float* qp = P + (size_t)token * QCOLS + h * 128;
        double q1d = 0., q2d = 0.;
#pragma unroll
        for (int s = 0; s < KSPLIT; s++) {
            q1d += (double)qp[(size_t)s * NTOK * QCOLS + lane];
            q2d += (double)qp[(size_t)s * NTOK * QCOLS + 64 + lane];
        }
        q1s[lane] = (float)q1d;
        q2s[lane] = (float)q2d;
    }
    __syncthreads();

    const float* kb = keys + (size_t)h * (NKn * 2 * DKn);
    const float4* ka0 = (const float4*)(kb + (size_t)(lane * 2 + 0) * DKn);
    const float4* ka1 = (const float4*)(kb + (size_t)((lane + 64) * 2 + 0) * DKn);
    const float4* kc0 = (const float4*)(kb + (size_t)(lane * 2 + 1) * DKn);
    const float4* kc1 = (const float4*)(kb + (size_t)((lane + 64) * 2 + 1) * DKn);
    const float4* q1v = (const float4*)q1s;
    const float4* q2v = (const float4*)q2s;

    double a0 = 0., a1 = 0., b0 = 0., b1 = 0.;
#pragma unroll
    for (int d = 0; d < DKn / 4; d++) {
        float4 q1 = q1v[d], q2 = q2v[d];
        float4 x0 = ka0[d], x1 = ka1[d], y0 = kc0[d], y1 = kc1[d];
        a0 = fma((double)q1.x, (double)x0.x, a0);
        a0 = fma((double)q1.y, (double)x0.y, a0);
        a0 = fma((double)q1.z, (double)x0.z, a0);
        a0 = fma((double)q1.w, (double)x0.w, a0);
        a1 = fma((double)q1.x, (double)x1.x, a1);
        a1 = fma((double)q1.y, (double)x1.y, a1);
        a1 = fma((double)q1.z, (double)x1.z, a1);
        a1 = fma((double)q1.w, (double)x1.w, a1);
        b0 = fma((double)q2.x, (double)y0.x, b0);
        b0 = fma((double)q2.y, (double)y0.y, b0);
        b0 = fma((double)q2.z, (double)y0.z, b0);
        b0 = fma((double)q2.w, (double)y0.w, b0);
        b1 = fma((double)q2.x, (double)y1.x, b1);
        b1 = fma((double)q2.y, (double)y1.y, b1);
        b1 = fma((double)q2.z, (double)y1.z, b1);
        b1 = fma((double)q2.w, (double)y1.w, b1);
    }

    // top-8 of sim1 (128 candidates: lane -> a0, lane+64 -> a1)
    double myS1 = 0., myS2 = 0.;
    int myI1 = 0, myI2 = 0;
    {
        double c0 = a0, c1 = a1;
#pragma unroll
        for (int r = 0; r < Kn; r++) {
            double v; int i;
            if (c1 > c0) { v = c1; i = lane + 64; } else { v = c0; i = lane; }
            argmax64d(v, i);
            if ((lane >> 3) == r) { myS1 = v; myI1 = i; }
            if (i == lane) c0 = -INFINITY;
            else if (i == lane + 64) c1 = -INFINITY;
        }
    }
    {
        double c0 = b0, c1 = b1;
#pragma unroll
        for (int r = 0; r < Kn; r++) {
            double v; int i;
            if (c1 > c0) { v = c1; i = lane + 64; } else { v = c0; i = lane; }
            argmax64d(v, i);
            if ((lane & 7) == r) { myS2 = v; myI2 = i; }
            if (i == lane) c0 = -INFINITY;
            else if (i == lane + 64) c1 = -INFINITY;
        }
    }

    // pair stage: lane = rank_i*8 + rank_j (matches reference flattened order)
    double c = myS1 + myS2;
    const int pidx = myI1 * NKn + myI2;
    double outS = 0.;
    int outI = 0;
#pragma unroll
    for (int r = 0; r < Kn; r++) {
        double v = c; int i = lane;
        argmax64d(v, i);
        int widx = __shfl(pidx, i);
        if (lane == r) { outS = v; outI = widx; }
        if (i == lane) c = -INFINITY;
    }

    if (lane < Kn) {
        fscore[(size_t)bth * Kn + lane] = (float)outS;
        fidx[(size_t)bth * Kn + lane] = outI;
    }
}

// ---------------------------------------------------------------------------
// Stage 3: expert gather + down-proj + silu*relu(score) + up-proj accumulate.
// One block (256 threads, 4 waves) per token. Each WAVE independently walks
// 8 experts — no barriers in the hot loop, 16 float4 loads in flight per
// lane per expert (vs 4 before), pure __shfl_xor reduce for the hidden dot.
// x is staged in LDS (reusing the final reduction buffer) to cap VGPRs.
// ---------------------------------------------------------------------------
__device__ inline float dot4(float4 a, float4 b) {
    return a.x * b.x + a.y * b.y + a.z * b.z + a.w * b.w;
}

__global__ __launch_bounds__(256) void expert_kernel(
    const float* __restrict__ x,       // [NTOK, Dsz]
    const float* __restrict__ e_down,  // [En, Dsz]
    const float* __restrict__ e_up,    // [En, Dsz]
    const int* __restrict__ fidx,      // [NTOK*Hn, Kn]
    const float* __restrict__ fscore,  // [NTOK*Hn, Kn]
    float* __restrict__ out)           // [NTOK, Dsz]
{
    const int token = blockIdx.x;
    const int tid = threadIdx.x;
    const int wid = tid >> 6;   // wave 0..3
    const int lane = tid & 63;

    // red[w][d]: per-wave partial output, 4 * 2048 * 4B = 32 KB.
    // red[0] doubles as the x staging buffer during the expert loop.
    __shared__ float red[4][Dsz];

    {   // stage x into red[0] (coalesced, once)
        const float4* xr = (const float4*)(x + (size_t)token * Dsz);
        float4* xs = (float4*)&red[0][0];
        xs[tid] = xr[tid];
        xs[tid + 256] = xr[tid + 256];
    }
    __syncthreads();

    const float4* xv = (const float4*)&red[0][0];

    float4 acc[8];
#pragma unroll
    for (int j = 0; j < 8; j++) acc[j] = make_float4(0.f, 0.f, 0.f, 0.f);

    const int* fi = fidx + (size_t)token * (Hn * Kn);
    const float* fs = fscore + (size_t)token * (Hn * Kn);

#pragma unroll 1
    for (int i = 0; i < 8; i++) {
        const int e = wid * 8 + i;          // this wave's expert stream
        const int idx = fi[e];
        const float sc = fs[e];
        const float4* wd = (const float4*)(e_down + (size_t)idx * Dsz);
        const float4* wu = (const float4*)(e_up + (size_t)idx * Dsz);

        float4 dv[8], uv[8];
#pragma unroll
        for (int j = 0; j < 8; j++) dv[j] = wd[lane + j * 64];
#pragma unroll
        for (int j = 0; j < 8; j++) uv[j] = wu[lane + j * 64];

        float p = 0.f;
#pragma unroll
        for (int j = 0; j < 8; j++) p += dot4(xv[lane + j * 64], dv[j]);
#pragma unroll
        for (int off = 1; off < 64; off <<= 1) p += __shfl_xor(p, off);

        const float act = (p / (1.f + expf(-p))) * fmaxf(sc, 0.f);
#pragma unroll
        for (int j = 0; j < 8; j++) {
            acc[j].x = fmaf(act, uv[j].x, acc[j].x);
            acc[j].y = fmaf(act, uv[j].y, acc[j].y);
            acc[j].z = fmaf(act, uv[j].z, acc[j].z);
            acc[j].w = fmaf(act, uv[j].w, acc[j].w);
        }
    }

    // all waves done reading x from red[0] before it is overwritten
    __syncthreads();
#pragma unroll
    for (int j = 0; j < 8; j++)
        *(float4*)&red[wid][(lane + j * 64) * 4] = acc[j];
    __syncthreads();

    float* o = out + (size_t)token * Dsz;
#pragma unroll
    for (int t = 0; t < 8; t++) {
        const int d = tid + t * 256;
        o[d] = red[0][d] + red[1][d] + red[2][d] + red[3][d];
    }
}

// ---------------------------------------------------------------------------
extern "C" void kernel_launch(void* const* d_in, const int* in_sizes, int n_in,
                              void* d_out, int out_size, void* d_ws, size_t ws_size,
                              hipStream_t stream) {
    const float* x      = (const float*)d_in[0];
    const float* Wq     = (const float*)d_in[1];
    const float* keys   = (const float*)d_in[2];
    const float* e_down = (const float*)d_in[3];
    const float* e_up   = (const float*)d_in[4];
    float* out = (float*)d_out;

    // workspace layout: P partials (16 MB) | fidx (256 KB) | fscore (256 KB)
    float* P = (float*)d_ws;
    int* fidx = (int*)((char*)d_ws + (size_t)(16 << 20));
    float* fscore = (float*)((char*)d_ws + (size_t)(16 << 20) + (256 << 10));

    dim3 g1(NTOK / GM, QCOLS / GN, KSPLIT);  // 32 x 8 x 4 = 1024 blocks
    gemm_q_kernel<<<g1, 256, 0, stream>>>(x, Wq, P);

    select_kernel<<<NTOK * Hn, 64, 0, stream>>>(P, keys, fidx, fscore);

    expert_kernel<<<NTOK, 256, 0, stream>>>(x, e_down, e_up, fidx, fscore, out);
}

// Round 2
// 577.326 us; speedup vs baseline: 1.0951x; 1.0951x over previous
//
#include <hip/hip_runtime.h>
#include <math.h>

// Problem constants
#define Bsz 2
#define Tsz 1024
#define Dsz 2048
#define Hn 4
#define Kn 8
#define DKn 64
#define En 16384
#define NKn 128
#define NTOK (Bsz * Tsz)      // 2048 tokens
#define QCOLS (2 * Hn * DKn)  // 512
#define KSPLIT 4
#define KCHUNK (Dsz / KSPLIT) // 512

// ---------------------------------------------------------------------------
// Stage 1: q partials = x @ Wq, split-K by 4.
// Grid (32, 8, 4) = 1024 blocks -> 4 blocks/CU, 16 waves/CU.
// fp32 accumulation within each 512-deep chunk (error ~1e-6 rel, 1000x below
// top-k flip margins); fp64 cross-chunk summation happens in select_kernel.
// 64x64 tile, BK=16, 256 threads, 4x4 microtile.
// ---------------------------------------------------------------------------
#define GM 64
#define GN 64
#define GK 16

__global__ __launch_bounds__(256) void gemm_q_kernel(
    const float* __restrict__ A,   // x: [NTOK, Dsz]
    const float* __restrict__ B,   // Wq: [Dsz, QCOLS]
    float* __restrict__ P)         // partials: [KSPLIT][NTOK][QCOLS]
{
    const int K = Dsz, N = QCOLS;
    __shared__ float As[GK][GM + 4];
    __shared__ float Bs[GK][GN + 4];

    const int tid = threadIdx.x;
    const int row0 = blockIdx.x * GM;
    const int col0 = blockIdx.y * GN;
    const int k0 = blockIdx.z * KCHUNK;
    const int tx = tid & 15;        // 0..15 (N dir)
    const int ty = tid >> 4;        // 0..15 (M dir)

    const int am = tid >> 2;
    const int ak = (tid & 3) << 2;
    const int bk = tid >> 4;
    const int bn = (tid & 15) << 2;

    float acc[4][4] = {};

    for (int kt = k0; kt < k0 + KCHUNK; kt += GK) {
        float4 av = *(const float4*)(A + (size_t)(row0 + am) * K + kt + ak);
        float4 bv = *(const float4*)(B + (size_t)(kt + bk) * N + col0 + bn);
        As[ak + 0][am] = av.x;
        As[ak + 1][am] = av.y;
        As[ak + 2][am] = av.z;
        As[ak + 3][am] = av.w;
        *(float4*)&Bs[bk][bn] = bv;
        __syncthreads();
#pragma unroll
        for (int k = 0; k < GK; k++) {
            float4 a = *(const float4*)&As[k][ty << 2];
            float4 b = *(const float4*)&Bs[k][tx << 2];
            acc[0][0] = fmaf(a.x, b.x, acc[0][0]);
            acc[0][1] = fmaf(a.x, b.y, acc[0][1]);
            acc[0][2] = fmaf(a.x, b.z, acc[0][2]);
            acc[0][3] = fmaf(a.x, b.w, acc[0][3]);
            acc[1][0] = fmaf(a.y, b.x, acc[1][0]);
            acc[1][1] = fmaf(a.y, b.y, acc[1][1]);
            acc[1][2] = fmaf(a.y, b.z, acc[1][2]);
            acc[1][3] = fmaf(a.y, b.w, acc[1][3]);
            acc[2][0] = fmaf(a.z, b.x, acc[2][0]);
            acc[2][1] = fmaf(a.z, b.y, acc[2][1]);
            acc[2][2] = fmaf(a.z, b.z, acc[2][2]);
            acc[2][3] = fmaf(a.z, b.w, acc[2][3]);
            acc[3][0] = fmaf(a.w, b.x, acc[3][0]);
            acc[3][1] = fmaf(a.w, b.y, acc[3][1]);
            acc[3][2] = fmaf(a.w, b.z, acc[3][2]);
            acc[3][3] = fmaf(a.w, b.w, acc[3][3]);
        }
        __syncthreads();
    }

    float* Pz = P + (size_t)blockIdx.z * NTOK * QCOLS;
#pragma unroll
    for (int i = 0; i < 4; i++) {
        float4 cv = make_float4(acc[i][0], acc[i][1], acc[i][2], acc[i][3]);
        *(float4*)(Pz + (size_t)(row0 + (ty << 2) + i) * N + col0 + (tx << 2)) = cv;
    }
}

// ---------------------------------------------------------------------------
// Stage 2: sum K-partials, sims + two-level top-k in fp64. One wave per (b,t,h).
// ---------------------------------------------------------------------------
__device__ inline void argmax64d(double& v, int& i) {
#pragma unroll
    for (int off = 1; off < 64; off <<= 1) {
        double ov = __shfl_xor(v, off);
        int oi = __shfl_xor(i, off);
        if (ov > v || (ov == v && oi < i)) { v = ov; i = oi; }
    }
}

__global__ __launch_bounds__(64) void select_kernel(
    const float* __restrict__ P,      // [KSPLIT][NTOK][QCOLS]
    const float* __restrict__ keys,   // [Hn, NKn, 2, DKn]
    int* __restrict__ fidx,           // [NTOK*Hn, Kn]
    float* __restrict__ fscore)       // [NTOK*Hn, Kn]
{
    const int bth = blockIdx.x;       // 8192
    const int token = bth >> 2;
    const int h = bth & 3;
    const int lane = threadIdx.x;

    __shared__ __align__(16) float q1s[64];
    __shared__ __align__(16) float q2s[64];
    {
        const float* qp = P + (size_t)token * QCOLS + h * 128;
        double q1d = 0., q2d = 0.;
#pragma unroll
        for (int s = 0; s < KSPLIT; s++) {
            q1d += (double)qp[(size_t)s * NTOK * QCOLS + lane];
            q2d += (double)qp[(size_t)s * NTOK * QCOLS + 64 + lane];
        }
        q1s[lane] = (float)q1d;
        q2s[lane] = (float)q2d;
    }
    __syncthreads();

    const float* kb = keys + (size_t)h * (NKn * 2 * DKn);
    const float4* ka0 = (const float4*)(kb + (size_t)(lane * 2 + 0) * DKn);
    const float4* ka1 = (const float4*)(kb + (size_t)((lane + 64) * 2 + 0) * DKn);
    const float4* kc0 = (const float4*)(kb + (size_t)(lane * 2 + 1) * DKn);
    const float4* kc1 = (const float4*)(kb + (size_t)((lane + 64) * 2 + 1) * DKn);
    const float4* q1v = (const float4*)q1s;
    const float4* q2v = (const float4*)q2s;

    double a0 = 0., a1 = 0., b0 = 0., b1 = 0.;
#pragma unroll
    for (int d = 0; d < DKn / 4; d++) {
        float4 q1 = q1v[d], q2 = q2v[d];
        float4 x0 = ka0[d], x1 = ka1[d], y0 = kc0[d], y1 = kc1[d];
        a0 = fma((double)q1.x, (double)x0.x, a0);
        a0 = fma((double)q1.y, (double)x0.y, a0);
        a0 = fma((double)q1.z, (double)x0.z, a0);
        a0 = fma((double)q1.w, (double)x0.w, a0);
        a1 = fma((double)q1.x, (double)x1.x, a1);
        a1 = fma((double)q1.y, (double)x1.y, a1);
        a1 = fma((double)q1.z, (double)x1.z, a1);
        a1 = fma((double)q1.w, (double)x1.w, a1);
        b0 = fma((double)q2.x, (double)y0.x, b0);
        b0 = fma((double)q2.y, (double)y0.y, b0);
        b0 = fma((double)q2.z, (double)y0.z, b0);
        b0 = fma((double)q2.w, (double)y0.w, b0);
        b1 = fma((double)q2.x, (double)y1.x, b1);
        b1 = fma((double)q2.y, (double)y1.y, b1);
        b1 = fma((double)q2.z, (double)y1.z, b1);
        b1 = fma((double)q2.w, (double)y1.w, b1);
    }

    // top-8 of sim1 (128 candidates: lane -> a0, lane+64 -> a1)
    double myS1 = 0., myS2 = 0.;
    int myI1 = 0, myI2 = 0;
    {
        double c0 = a0, c1 = a1;
#pragma unroll
        for (int r = 0; r < Kn; r++) {
            double v; int i;
            if (c1 > c0) { v = c1; i = lane + 64; } else { v = c0; i = lane; }
            argmax64d(v, i);
            if ((lane >> 3) == r) { myS1 = v; myI1 = i; }
            if (i == lane) c0 = -INFINITY;
            else if (i == lane + 64) c1 = -INFINITY;
        }
    }
    {
        double c0 = b0, c1 = b1;
#pragma unroll
        for (int r = 0; r < Kn; r++) {
            double v; int i;
            if (c1 > c0) { v = c1; i = lane + 64; } else { v = c0; i = lane; }
            argmax64d(v, i);
            if ((lane & 7) == r) { myS2 = v; myI2 = i; }
            if (i == lane) c0 = -INFINITY;
            else if (i == lane + 64) c1 = -INFINITY;
        }
    }

    // pair stage: lane = rank_i*8 + rank_j (matches reference flattened order)
    double c = myS1 + myS2;
    const int pidx = myI1 * NKn + myI2;
    double outS = 0.;
    int outI = 0;
#pragma unroll
    for (int r = 0; r < Kn; r++) {
        double v = c; int i = lane;
        argmax64d(v, i);
        int widx = __shfl(pidx, i);
        if (lane == r) { outS = v; outI = widx; }
        if (i == lane) c = -INFINITY;
    }

    if (lane < Kn) {
        fscore[(size_t)bth * Kn + lane] = (float)outS;
        fidx[(size_t)bth * Kn + lane] = outI;
    }
}

// ---------------------------------------------------------------------------
// Stage 3: expert gather + down-proj + silu*relu(score) + up-proj accumulate.
// One block (256 threads, 4 waves) per token; each wave owns 8 experts, no
// barriers in the hot loop. LDS cut to 16 KB (xs + red) so occupancy is
// capped by the 32-wave/CU limit (8 blocks/CU) instead of LDS (was 5).
// Cross-wave combine: serialized adds into red (deterministic w0+w1+w2+w3).
// ---------------------------------------------------------------------------
__device__ inline float dot4(float4 a, float4 b) {
    return a.x * b.x + a.y * b.y + a.z * b.z + a.w * b.w;
}

__global__ __launch_bounds__(256) void expert_kernel(
    const float* __restrict__ x,       // [NTOK, Dsz]
    const float* __restrict__ e_down,  // [En, Dsz]
    const float* __restrict__ e_up,    // [En, Dsz]
    const int* __restrict__ fidx,      // [NTOK*Hn, Kn]
    const float* __restrict__ fscore,  // [NTOK*Hn, Kn]
    float* __restrict__ out)           // [NTOK, Dsz]
{
    const int token = blockIdx.x;
    const int tid = threadIdx.x;
    const int wid = tid >> 6;   // wave 0..3
    const int lane = tid & 63;

    __shared__ float xs[Dsz];    // 8 KB: staged x
    __shared__ float red[Dsz];   // 8 KB: cross-wave output accumulator

    {   // stage x (coalesced, once)
        const float4* xr = (const float4*)(x + (size_t)token * Dsz);
        float4* xv = (float4*)xs;
        xv[tid] = xr[tid];
        xv[tid + 256] = xr[tid + 256];
    }
    __syncthreads();

    const float4* xv = (const float4*)xs;

    float4 acc[8];
#pragma unroll
    for (int j = 0; j < 8; j++) acc[j] = make_float4(0.f, 0.f, 0.f, 0.f);

    const int* fi = fidx + (size_t)token * (Hn * Kn);
    const float* fs = fscore + (size_t)token * (Hn * Kn);

#pragma unroll 1
    for (int i = 0; i < 8; i++) {
        const int e = wid * 8 + i;          // this wave's expert stream
        const int idx = fi[e];
        const float sc = fs[e];
        const float4* wd = (const float4*)(e_down + (size_t)idx * Dsz);
        const float4* wu = (const float4*)(e_up + (size_t)idx * Dsz);

        float4 dv[8], uv[8];
#pragma unroll
        for (int j = 0; j < 8; j++) dv[j] = wd[lane + j * 64];
#pragma unroll
        for (int j = 0; j < 8; j++) uv[j] = wu[lane + j * 64];

        float p = 0.f;
#pragma unroll
        for (int j = 0; j < 8; j++) p += dot4(xv[lane + j * 64], dv[j]);
#pragma unroll
        for (int off = 1; off < 64; off <<= 1) p += __shfl_xor(p, off);

        const float act = (p / (1.f + expf(-p))) * fmaxf(sc, 0.f);
#pragma unroll
        for (int j = 0; j < 8; j++) {
            acc[j].x = fmaf(act, uv[j].x, acc[j].x);
            acc[j].y = fmaf(act, uv[j].y, acc[j].y);
            acc[j].z = fmaf(act, uv[j].z, acc[j].z);
            acc[j].w = fmaf(act, uv[j].w, acc[j].w);
        }
    }

    // deterministic cross-wave sum: red = ((w0 + w1) + w2) + w3
    __syncthreads();
#pragma unroll 1
    for (int w = 0; w < 4; w++) {
        if (wid == w) {
            if (w == 0) {
#pragma unroll
                for (int j = 0; j < 8; j++)
                    *(float4*)&red[(lane + j * 64) * 4] = acc[j];
            } else {
#pragma unroll
                for (int j = 0; j < 8; j++) {
                    float4 r = *(const float4*)&red[(lane + j * 64) * 4];
                    r.x += acc[j].x; r.y += acc[j].y;
                    r.z += acc[j].z; r.w += acc[j].w;
                    *(float4*)&red[(lane + j * 64) * 4] = r;
                }
            }
        }
        __syncthreads();
    }

    float4* o = (float4*)(out + (size_t)token * Dsz);
    const float4* rv = (const float4*)red;
    o[tid] = rv[tid];
    o[tid + 256] = rv[tid + 256];
}

// ---------------------------------------------------------------------------
extern "C" void kernel_launch(void* const* d_in, const int* in_sizes, int n_in,
                              void* d_out, int out_size, void* d_ws, size_t ws_size,
                              hipStream_t stream) {
    const float* x      = (const float*)d_in[0];
    const float* Wq     = (const float*)d_in[1];
    const float* keys   = (const float*)d_in[2];
    const float* e_down = (const float*)d_in[3];
    const float* e_up   = (const float*)d_in[4];
    float* out = (float*)d_out;

    // workspace layout: P partials (16 MB) | fidx (256 KB) | fscore (256 KB)
    float* P = (float*)d_ws;
    int* fidx = (int*)((char*)d_ws + (size_t)(16 << 20));
    float* fscore = (float*)((char*)d_ws + (size_t)(16 << 20) + (256 << 10));

    dim3 g1(NTOK / GM, QCOLS / GN, KSPLIT);  // 32 x 8 x 4 = 1024 blocks
    gemm_q_kernel<<<g1, 256, 0, stream>>>(x, Wq, P);

    select_kernel<<<NTOK * Hn, 64, 0, stream>>>(P, keys, fidx, fscore);

    expert_kernel<<<NTOK, 256, 0, stream>>>(x, e_down, e_up, fidx, fscore, out);
}

// Round 3
// 493.024 us; speedup vs baseline: 1.2824x; 1.1710x over previous
//
#include <hip/hip_runtime.h>
#include <math.h>

// Problem constants
#define Bsz 2
#define Tsz 1024
#define Dsz 2048
#define Hn 4
#define Kn 8
#define DKn 64
#define En 16384
#define NKn 128
#define NTOK (Bsz * Tsz)      // 2048 tokens
#define QCOLS (2 * Hn * DKn)  // 512
#define KSPLIT 4
#define KCHUNK (Dsz / KSPLIT) // 512

// ---------------------------------------------------------------------------
// Stage 0: transpose keys [H][NK][2][DK] -> keysT [H][2][DK][NK] so the
// select kernel's per-lane key reads are lane-contiguous (coalesced).
// 65536 elements, trivial.
// ---------------------------------------------------------------------------
__global__ __launch_bounds__(256) void transpose_keys_kernel(
    const float* __restrict__ keys, float* __restrict__ keysT)
{
    const int idx = blockIdx.x * 256 + threadIdx.x;   // 0..65535
    const int h = idx >> 14;
    const int rem = idx & 16383;
    const int n = rem >> 7;
    const int s = (rem >> 6) & 1;
    const int d = rem & 63;
    keysT[(((size_t)h * 2 + s) * DKn + d) * NKn + n] = keys[idx];
}

// ---------------------------------------------------------------------------
// Stage 1: q partials = x @ Wq, split-K by 4.
// Grid (32, 8, 4) = 1024 blocks -> 4 blocks/CU, 16 waves/CU.
// fp32 accumulation within each 512-deep chunk; fp64 cross-chunk sum in select.
// 64x64 tile, BK=16, 256 threads, 4x4 microtile.
// v3: register-staged double buffer — global loads for tile k+1 issue right
// after the barrier and drain during the 512-FMA compute phase (the waitcnt
// lands before next iteration's LDS write). FMA order unchanged vs v2.
// ---------------------------------------------------------------------------
#define GM 64
#define GN 64
#define GK 16

__global__ __launch_bounds__(256) void gemm_q_kernel(
    const float* __restrict__ A,   // x: [NTOK, Dsz]
    const float* __restrict__ B,   // Wq: [Dsz, QCOLS]
    float* __restrict__ P)         // partials: [KSPLIT][NTOK][QCOLS]
{
    const int K = Dsz, N = QCOLS;
    __shared__ float As[GK][GM + 4];
    __shared__ float Bs[GK][GN + 4];

    const int tid = threadIdx.x;
    const int row0 = blockIdx.x * GM;
    const int col0 = blockIdx.y * GN;
    const int k0 = blockIdx.z * KCHUNK;
    const int tx = tid & 15;        // 0..15 (N dir)
    const int ty = tid >> 4;        // 0..15 (M dir)

    const int am = tid >> 2;
    const int ak = (tid & 3) << 2;
    const int bk = tid >> 4;
    const int bn = (tid & 15) << 2;

    float acc[4][4] = {};

    // prologue prefetch of tile k0
    float4 av = *(const float4*)(A + (size_t)(row0 + am) * K + k0 + ak);
    float4 bv = *(const float4*)(B + (size_t)(k0 + bk) * N + col0 + bn);

    for (int kt = k0; kt < k0 + KCHUNK; kt += GK) {
        As[ak + 0][am] = av.x;
        As[ak + 1][am] = av.y;
        As[ak + 2][am] = av.z;
        As[ak + 3][am] = av.w;
        *(float4*)&Bs[bk][bn] = bv;
        __syncthreads();

        // prefetch next tile into regs; consumed only at next LDS write
        if (kt + GK < k0 + KCHUNK) {
            av = *(const float4*)(A + (size_t)(row0 + am) * K + (kt + GK) + ak);
            bv = *(const float4*)(B + (size_t)(kt + GK + bk) * N + col0 + bn);
        }

#pragma unroll
        for (int k = 0; k < GK; k++) {
            float4 a = *(const float4*)&As[k][ty << 2];
            float4 b = *(const float4*)&Bs[k][tx << 2];
            acc[0][0] = fmaf(a.x, b.x, acc[0][0]);
            acc[0][1] = fmaf(a.x, b.y, acc[0][1]);
            acc[0][2] = fmaf(a.x, b.z, acc[0][2]);
            acc[0][3] = fmaf(a.x, b.w, acc[0][3]);
            acc[1][0] = fmaf(a.y, b.x, acc[1][0]);
            acc[1][1] = fmaf(a.y, b.y, acc[1][1]);
            acc[1][2] = fmaf(a.y, b.z, acc[1][2]);
            acc[1][3] = fmaf(a.y, b.w, acc[1][3]);
            acc[2][0] = fmaf(a.z, b.x, acc[2][0]);
            acc[2][1] = fmaf(a.z, b.y, acc[2][1]);
            acc[2][2] = fmaf(a.z, b.z, acc[2][2]);
            acc[2][3] = fmaf(a.z, b.w, acc[2][3]);
            acc[3][0] = fmaf(a.w, b.x, acc[3][0]);
            acc[3][1] = fmaf(a.w, b.y, acc[3][1]);
            acc[3][2] = fmaf(a.w, b.z, acc[3][2]);
            acc[3][3] = fmaf(a.w, b.w, acc[3][3]);
        }
        __syncthreads();
    }

    float* Pz = P + (size_t)blockIdx.z * NTOK * QCOLS;
#pragma unroll
    for (int i = 0; i < 4; i++) {
        float4 cv = make_float4(acc[i][0], acc[i][1], acc[i][2], acc[i][3]);
        *(float4*)(Pz + (size_t)(row0 + (ty << 2) + i) * N + col0 + (tx << 2)) = cv;
    }
}

// ---------------------------------------------------------------------------
// Stage 2: sum K-partials, sims + two-level top-k in fp64. One wave per (b,t,h).
// v3: keys read from the transposed layout keysT[h][s][d][n] — lane-contiguous
// (4 cache lines per wave instr instead of 64). fp64 fma sequence per
// accumulator is identical to v2 (d ascending) -> bitwise-identical sims.
// ---------------------------------------------------------------------------
__device__ inline void argmax64d(double& v, int& i) {
#pragma unroll
    for (int off = 1; off < 64; off <<= 1) {
        double ov = __shfl_xor(v, off);
        int oi = __shfl_xor(i, off);
        if (ov > v || (ov == v && oi < i)) { v = ov; i = oi; }
    }
}

__global__ __launch_bounds__(64) void select_kernel(
    const float* __restrict__ P,      // [KSPLIT][NTOK][QCOLS]
    const float* __restrict__ keysT,  // [Hn, 2, DKn, NKn]
    int* __restrict__ fidx,           // [NTOK*Hn, Kn]
    float* __restrict__ fscore)       // [NTOK*Hn, Kn]
{
    const int bth = blockIdx.x;       // 8192
    const int token = bth >> 2;
    const int h = bth & 3;
    const int lane = threadIdx.x;

    __shared__ __align__(16) float q1s[64];
    __shared__ __align__(16) float q2s[64];
    {
        const float* qp = P + (size_t)token * QCOLS + h * 128;
        double q1d = 0., q2d = 0.;
#pragma unroll
        for (int s = 0; s < KSPLIT; s++) {
            q1d += (double)qp[(size_t)s * NTOK * QCOLS + lane];
            q2d += (double)qp[(size_t)s * NTOK * QCOLS + 64 + lane];
        }
        q1s[lane] = (float)q1d;
        q2s[lane] = (float)q2d;
    }
    __syncthreads();

    const float* kT = keysT + (size_t)h * (2 * DKn * NKn);

    double a0 = 0., a1 = 0., b0 = 0., b1 = 0.;
#pragma unroll 8
    for (int d = 0; d < DKn; d++) {
        const double q1 = (double)q1s[d];
        const double q2 = (double)q2s[d];
        const float k0a = kT[d * NKn + lane];
        const float k1a = kT[d * NKn + lane + 64];
        const float k0b = kT[(DKn + d) * NKn + lane];
        const float k1b = kT[(DKn + d) * NKn + lane + 64];
        a0 = fma(q1, (double)k0a, a0);
        a1 = fma(q1, (double)k1a, a1);
        b0 = fma(q2, (double)k0b, b0);
        b1 = fma(q2, (double)k1b, b1);
    }

    // top-8 of sim1 (128 candidates: lane -> a0, lane+64 -> a1)
    double myS1 = 0., myS2 = 0.;
    int myI1 = 0, myI2 = 0;
    {
        double c0 = a0, c1 = a1;
#pragma unroll
        for (int r = 0; r < Kn; r++) {
            double v; int i;
            if (c1 > c0) { v = c1; i = lane + 64; } else { v = c0; i = lane; }
            argmax64d(v, i);
            if ((lane >> 3) == r) { myS1 = v; myI1 = i; }
            if (i == lane) c0 = -INFINITY;
            else if (i == lane + 64) c1 = -INFINITY;
        }
    }
    {
        double c0 = b0, c1 = b1;
#pragma unroll
        for (int r = 0; r < Kn; r++) {
            double v; int i;
            if (c1 > c0) { v = c1; i = lane + 64; } else { v = c0; i = lane; }
            argmax64d(v, i);
            if ((lane & 7) == r) { myS2 = v; myI2 = i; }
            if (i == lane) c0 = -INFINITY;
            else if (i == lane + 64) c1 = -INFINITY;
        }
    }

    // pair stage: lane = rank_i*8 + rank_j (matches reference flattened order)
    double c = myS1 + myS2;
    const int pidx = myI1 * NKn + myI2;
    double outS = 0.;
    int outI = 0;
#pragma unroll
    for (int r = 0; r < Kn; r++) {
        double v = c; int i = lane;
        argmax64d(v, i);
        int widx = __shfl(pidx, i);
        if (lane == r) { outS = v; outI = widx; }
        if (i == lane) c = -INFINITY;
    }

    if (lane < Kn) {
        fscore[(size_t)bth * Kn + lane] = (float)outS;
        fidx[(size_t)bth * Kn + lane] = outI;
    }
}

// ---------------------------------------------------------------------------
// Stage 3: expert gather + down-proj + silu*relu(score) + up-proj accumulate.
// One block (256 threads, 4 waves) per token; each wave owns 8 experts, no
// barriers in the hot loop. Delivered-BW-bound at ~5.8 TB/s aggregate
// (HBM 3.0 TB/s + L3) — at its structural roofline; unchanged.
// ---------------------------------------------------------------------------
__device__ inline float dot4(float4 a, float4 b) {
    return a.x * b.x + a.y * b.y + a.z * b.z + a.w * b.w;
}

__global__ __launch_bounds__(256) void expert_kernel(
    const float* __restrict__ x,       // [NTOK, Dsz]
    const float* __restrict__ e_down,  // [En, Dsz]
    const float* __restrict__ e_up,    // [En, Dsz]
    const int* __restrict__ fidx,      // [NTOK*Hn, Kn]
    const float* __restrict__ fscore,  // [NTOK*Hn, Kn]
    float* __restrict__ out)           // [NTOK, Dsz]
{
    const int token = blockIdx.x;
    const int tid = threadIdx.x;
    const int wid = tid >> 6;   // wave 0..3
    const int lane = tid & 63;

    __shared__ float xs[Dsz];    // 8 KB: staged x
    __shared__ float red[Dsz];   // 8 KB: cross-wave output accumulator

    {   // stage x (coalesced, once)
        const float4* xr = (const float4*)(x + (size_t)token * Dsz);
        float4* xv = (float4*)xs;
        xv[tid] = xr[tid];
        xv[tid + 256] = xr[tid + 256];
    }
    __syncthreads();

    const float4* xv = (const float4*)xs;

    float4 acc[8];
#pragma unroll
    for (int j = 0; j < 8; j++) acc[j] = make_float4(0.f, 0.f, 0.f, 0.f);

    const int* fi = fidx + (size_t)token * (Hn * Kn);
    const float* fs = fscore + (size_t)token * (Hn * Kn);

#pragma unroll 1
    for (int i = 0; i < 8; i++) {
        const int e = wid * 8 + i;          // this wave's expert stream
        const int idx = fi[e];
        const float sc = fs[e];
        const float4* wd = (const float4*)(e_down + (size_t)idx * Dsz);
        const float4* wu = (const float4*)(e_up + (size_t)idx * Dsz);

        float4 dv[8], uv[8];
#pragma unroll
        for (int j = 0; j < 8; j++) dv[j] = wd[lane + j * 64];
#pragma unroll
        for (int j = 0; j < 8; j++) uv[j] = wu[lane + j * 64];

        float p = 0.f;
#pragma unroll
        for (int j = 0; j < 8; j++) p += dot4(xv[lane + j * 64], dv[j]);
#pragma unroll
        for (int off = 1; off < 64; off <<= 1) p += __shfl_xor(p, off);

        const float act = (p / (1.f + expf(-p))) * fmaxf(sc, 0.f);
#pragma unroll
        for (int j = 0; j < 8; j++) {
            acc[j].x = fmaf(act, uv[j].x, acc[j].x);
            acc[j].y = fmaf(act, uv[j].y, acc[j].y);
            acc[j].z = fmaf(act, uv[j].z, acc[j].z);
            acc[j].w = fmaf(act, uv[j].w, acc[j].w);
        }
    }

    // deterministic cross-wave sum: red = ((w0 + w1) + w2) + w3
    __syncthreads();
#pragma unroll 1
    for (int w = 0; w < 4; w++) {
        if (wid == w) {
            if (w == 0) {
#pragma unroll
                for (int j = 0; j < 8; j++)
                    *(float4*)&red[(lane + j * 64) * 4] = acc[j];
            } else {
#pragma unroll
                for (int j = 0; j < 8; j++) {
                    float4 r = *(const float4*)&red[(lane + j * 64) * 4];
                    r.x += acc[j].x; r.y += acc[j].y;
                    r.z += acc[j].z; r.w += acc[j].w;
                    *(float4*)&red[(lane + j * 64) * 4] = r;
                }
            }
        }
        __syncthreads();
    }

    float4* o = (float4*)(out + (size_t)token * Dsz);
    const float4* rv = (const float4*)red;
    o[tid] = rv[tid];
    o[tid + 256] = rv[tid + 256];
}

// ---------------------------------------------------------------------------
extern "C" void kernel_launch(void* const* d_in, const int* in_sizes, int n_in,
                              void* d_out, int out_size, void* d_ws, size_t ws_size,
                              hipStream_t stream) {
    const float* x      = (const float*)d_in[0];
    const float* Wq     = (const float*)d_in[1];
    const float* keys   = (const float*)d_in[2];
    const float* e_down = (const float*)d_in[3];
    const float* e_up   = (const float*)d_in[4];
    float* out = (float*)d_out;

    // workspace: P (16 MB) | fidx (256 KB) | fscore (256 KB) | keysT (256 KB)
    float* P = (float*)d_ws;
    int* fidx = (int*)((char*)d_ws + (size_t)(16 << 20));
    float* fscore = (float*)((char*)d_ws + (size_t)(16 << 20) + (256 << 10));
    float* keysT = (float*)((char*)d_ws + (size_t)(16 << 20) + (512 << 10));

    transpose_keys_kernel<<<256, 256, 0, stream>>>(keys, keysT);

    dim3 g1(NTOK / GM, QCOLS / GN, KSPLIT);  // 32 x 8 x 4 = 1024 blocks
    gemm_q_kernel<<<g1, 256, 0, stream>>>(x, Wq, P);

    select_kernel<<<NTOK * Hn, 64, 0, stream>>>(P, keysT, fidx, fscore);

    expert_kernel<<<NTOK, 256, 0, stream>>>(x, e_down, e_up, fidx, fscore, out);
}